// Round 1
// baseline (852.916 us; speedup 1.0000x reference)
//
#include <hip/hip_runtime.h>

#define H 64
#define NE 1500000
#define NLOC 20000
#define NEXP 200000
#define NL 400000
#define PAD_E 32
#define PAD_L 128
#define EPT 8
#define FILL_CHUNK 2048
#define NCHUNK ((NE + FILL_CHUNK - 1) / FILL_CHUNK)   // 733
#define NDT ((NLOC + 63) / 64)                        // 313 dense-row tickets
#define NFILL 1536

// ---- workspace layout (bytes) ----
// cnt_loc [0,80000)  cnt_exp [80000,880000)  tickets [880000,880040)
// nbr_loc [880064,11120064)  nbr_exp(u16) [11120064,23920064)
// Ylh(f16)  [23920064,26480064)   Y2fh(f16) [26480064,29040064)
// z_loc(f32)[29040064,34160064)   PH(f16)   [34160064,36720064)
// ZE(f16)   [39280064,64880064)   z_exph -> Qh (in-place)
// TH(f16)   [64880064,90480064)   T1h -> T2'h
// Wf_q [90480064) Wf_y2 [90496448) Wf_t2 [90512832) Wf_p [90529216)
// bf_q [90545600) bf_p [90545856)
#define WS_NEED 90546112ULL

typedef int vint4 __attribute__((ext_vector_type(4)));
typedef _Float16 f16x8 __attribute__((ext_vector_type(8)));
typedef float f32x4 __attribute__((ext_vector_type(4)));

__device__ __forceinline__ float bcastf(float v, int k) {
  return __int_as_float(__builtin_amdgcn_readlane(__float_as_int(v), k));
}
__device__ __forceinline__ int bcasti(int v, int k) {
  return __builtin_amdgcn_readlane(v, k);
}

// Persistent mega-kernel: fold (5 tickets) -> dense Ylh (313 tickets) ->
// CSR fill via per-partition ticket queues with PHYSICAL XCD affinity.
//
// r0 theory: blockIdx&7 != XCD on this dispatch path (WRITE_SIZE showed 5.5x
// L2 thrash). Here each block reads HW_REG_XCC_ID and drains its own XCD's
// partition queue first; cross-partition fallback keeps exactly-once
// correctness independent of the dispatch mapping (atomic tickets).
__global__ __launch_bounds__(256) void mega_kernel(
    const int* __restrict__ src, const int* __restrict__ dst,
    int* __restrict__ cnt_loc, int* __restrict__ cnt_exp,
    int* __restrict__ nbr_loc, unsigned short* __restrict__ nbr_exp,
    int* __restrict__ tickets,
    const float* __restrict__ emb_loc, _Float16* __restrict__ Ylh,
    const float* __restrict__ W1l_of,
    const float* __restrict__ W2r_of, const float* __restrict__ W2l_of,
    const float* __restrict__ W2l_rev, const float* __restrict__ W2r_rev,
    const float* __restrict__ dW1, const float* __restrict__ b2_of,
    const float* __restrict__ b2_rev,
    float* __restrict__ Wf_q, float* __restrict__ Wf_y2,
    float* __restrict__ Wf_t2, float* __restrict__ Wf_p,
    float* __restrict__ bf_q, float* __restrict__ bf_p)
{
  const int lane = threadIdx.x & 63;
  const int w = threadIdx.x >> 6;
  __shared__ int s_t;

  // ---------- phase 0: weight folding (tickets[9], 5 items) ----------
  while (true) {
    __syncthreads();
    if (threadIdx.x == 0) {
      int c = __hip_atomic_load(&tickets[9], __ATOMIC_RELAXED,
                                __HIP_MEMORY_SCOPE_AGENT);
      s_t = (c >= 5) ? 5 : atomicAdd(&tickets[9], 1);
    }
    __syncthreads();
    const int t = s_t;
    if (t >= 5) break;
    const float* dW1a = dW1;
    const float* dW1b = dW1 + H * H;
    if (t < 4) {
      const float* A; const float* B; float* C;
      switch (t) {
        case 0:  A = W2r_of;  B = dW1b; C = Wf_q;  break;
        case 1:  A = W2l_of;  B = dW1b; C = Wf_y2; break;
        case 2:  A = W2l_rev; B = dW1a; C = Wf_t2; break;
        default: A = W2r_rev; B = dW1a; C = Wf_p;  break;
      }
      float b[H];
#pragma unroll
      for (int k = 0; k < H; k++) b[k] = B[k * H + lane];
      for (int r = w * 16; r < w * 16 + 16; r++) {
        const float xv = A[r * H + lane];
        float a0 = 0.f, a1 = 0.f;
#pragma unroll
        for (int k = 0; k < H; k += 2) {
          a0 += bcastf(xv, k)     * b[k];
          a1 += bcastf(xv, k + 1) * b[k + 1];
        }
        C[r * H + lane] = a0 + a1;
      }
    } else if (w < 2) {
      const float* bv_src = (w == 0) ? b2_of : b2_rev;
      const float* B      = (w == 0) ? dW1b  : dW1a;
      float* o            = (w == 0) ? bf_q  : bf_p;
      float wk[H];
#pragma unroll
      for (int k = 0; k < H; k++) wk[k] = B[k * H + lane];
      const float bv = bv_src[lane];
      float a = 0.f;
#pragma unroll
      for (int k = 0; k < H; k++) a += bcastf(bv, k) * wk[k];
      o[lane] = a;
    }
  }

  // ---------- phase 1: Ylh = (emb_loc @ W1l_of) fp16 (tickets[8]) ----------
  {
    bool wl = false;
    float wreg[H];
    while (true) {
      __syncthreads();
      if (threadIdx.x == 0) {
        int c = __hip_atomic_load(&tickets[8], __ATOMIC_RELAXED,
                                  __HIP_MEMORY_SCOPE_AGENT);
        s_t = (c >= NDT) ? NDT : atomicAdd(&tickets[8], 1);
      }
      __syncthreads();
      const int t = s_t;
      if (t >= NDT) break;
      if (!wl) {
        wl = true;
#pragma unroll
        for (int k = 0; k < H; k++) wreg[k] = W1l_of[k * H + lane];
      }
      const int rbase = t * 64 + w * 16;
      for (int rr = 0; rr < 16; rr++) {
        const int r = rbase + rr;
        if (r >= NLOC) break;
        const float xv = emb_loc[r * H + lane];
        float a0 = 0.f, a1 = 0.f;
#pragma unroll
        for (int k = 0; k < H; k += 2) {
          a0 += bcastf(xv, k)     * wreg[k];
          a1 += bcastf(xv, k + 1) * wreg[k + 1];
        }
        Ylh[(long)r * H + lane] = (_Float16)(a0 + a1);
      }
    }
  }

  // ---------- phase 2: CSR fill with physical-XCD affinity ----------
  // hwreg(id=20 HW_REG_XCC_ID, offset=0, size=4) -> imm 20 | (4-1)<<11 = 6164
  const int xcd = (int)(__builtin_amdgcn_s_getreg(6164) & 7);
  for (int pi = 0; pi < 8; pi++) {
    const int p = (xcd + pi) & 7;
    const int elo = p * (NEXP / 8), ehi = elo + NEXP / 8;
    const int llo = p * (NLOC / 8), lhi = llo + NLOC / 8;
    while (true) {
      __syncthreads();
      if (threadIdx.x == 0) {
        int c = __hip_atomic_load(&tickets[p], __ATOMIC_RELAXED,
                                  __HIP_MEMORY_SCOPE_AGENT);
        s_t = (c >= NCHUNK) ? NCHUNK : atomicAdd(&tickets[p], 1);
      }
      __syncthreads();
      const int chunk = s_t;
      if (chunk >= NCHUNK) break;
      const long base = (long)chunk * FILL_CHUNK + threadIdx.x * EPT;
      if (base < NE) {
        vint4 s0 = __builtin_nontemporal_load((const vint4*)(src + base));
        vint4 s1 = __builtin_nontemporal_load((const vint4*)(src + base + 4));
        vint4 d0 = __builtin_nontemporal_load((const vint4*)(dst + base));
        vint4 d1 = __builtin_nontemporal_load((const vint4*)(dst + base + 4));
        int ss[EPT] = {s0.x, s0.y, s0.z, s0.w, s1.x, s1.y, s1.z, s1.w};
        int dd[EPT] = {d0.x, d0.y, d0.z, d0.w, d1.x, d1.y, d1.z, d1.w};
#pragma unroll
        for (int k = 0; k < EPT; k++) {
          const int d = dd[k];
          if (d >= elo && d < ehi) {
            int pos = atomicAdd(&cnt_exp[d], 1);
            if (pos < PAD_E) nbr_exp[d * PAD_E + pos] = (unsigned short)ss[k];
          }
        }
#pragma unroll
        for (int k = 0; k < EPT; k++) {
          const int s = ss[k];
          if (s >= llo && s < lhi) {
            int pos = atomicAdd(&cnt_loc[s], 1);
            if (pos < PAD_L) nbr_loc[s * PAD_L + pos] = dd[k];
          }
        }
      }
    }
  }
}

// out16 = x @ W (no bias); fp32 in, fp16 out. 20K rows.
__global__ __launch_bounds__(256, 4) void dense_linear_kernel(
    const float* __restrict__ x, _Float16* __restrict__ out16,
    const float* __restrict__ W, int n)
{
  const int lane = threadIdx.x & 63;
  const int gw = (blockIdx.x * 256 + threadIdx.x) >> 6;
  const int nw = (gridDim.x * 256) >> 6;
  float w[H];
#pragma unroll
  for (int k = 0; k < H; k++) w[k] = W[k * H + lane];
  for (int i = gw; i < n; i += nw) {
    const float xv = x[i * H + lane];
    float a0 = 0.f, a1 = 0.f;
#pragma unroll
    for (int k = 0; k < H; k += 2) {
      a0 += bcastf(xv, k)     * w[k];
      a1 += bcastf(xv, k + 1) * w[k + 1];
    }
    out16[i * H + lane] = (_Float16)(a0 + a1);
  }
}

// Exp-side MFMA pass (dual-B, optional gather/bias/relu). Block = 16 rows.
__global__ __launch_bounds__(256, 4) void mfma_pass_kernel(
    const unsigned short* __restrict__ nbr, const int* __restrict__ cnt,
    const _Float16* __restrict__ y,
    const float* a32, const _Float16* a16,
    _Float16* out1, const float* __restrict__ W1,
    const float* __restrict__ bias, int relu,
    _Float16* out2, const float* __restrict__ W2)
{
  const int w = threadIdx.x >> 6;
  const int lane = threadIdx.x & 63;
  const int q = lane >> 4;
  const int cidx = lane & 15;
  const int rb = blockIdx.x * 16;

  __shared__ float Gs[16 * H];

  f16x8 b1lo, b1hi, b2lo, b2hi;
#pragma unroll
  for (int j = 0; j < 8; j++) {
    b1lo[j] = (_Float16)W1[(q * 8 + j) * H + w * 16 + cidx];
    b1hi[j] = (_Float16)W1[(32 + q * 8 + j) * H + w * 16 + cidx];
  }
  if (out2) {
#pragma unroll
    for (int j = 0; j < 8; j++) {
      b2lo[j] = (_Float16)W2[(q * 8 + j) * H + w * 16 + cidx];
      b2hi[j] = (_Float16)W2[(32 + q * 8 + j) * H + w * 16 + cidx];
    }
  }

  if (y) {
    for (int rr = 0; rr < 4; rr++) {
      const int i = rb + w * 4 + rr;
      const int c = cnt[i];
      const int cc = min(c, PAD_E);
      const unsigned short* nb = nbr + (long)i * PAD_E;
      float s0 = 0.f, s1 = 0.f, s2 = 0.f, s3 = 0.f;
      const int id = (lane < cc) ? (int)nb[lane] : 0;
      int k = 0;
      const int m4 = cc & ~3;
      for (; k < m4; k += 4) {
        const int i0 = bcasti(id, k), i1 = bcasti(id, k + 1),
                  i2 = bcasti(id, k + 2), i3 = bcasti(id, k + 3);
        s0 += (float)y[(long)i0 * H + lane];
        s1 += (float)y[(long)i1 * H + lane];
        s2 += (float)y[(long)i2 * H + lane];
        s3 += (float)y[(long)i3 * H + lane];
      }
      for (; k < cc; k++) s0 += (float)y[(long)bcasti(id, k) * H + lane];
      Gs[(w * 4 + rr) * H + lane] =
          ((s0 + s1) + (s2 + s3)) / fmaxf((float)c, 1.0f);
    }
  }

  f16x8 a0, a1;
  if (a16) {
    const _Float16* ar = a16 + (long)(rb + cidx) * H;
    a0 = *(const f16x8*)(ar + q * 8);
    a1 = *(const f16x8*)(ar + 32 + q * 8);
  } else {
    const float* ar = a32 + (long)(rb + cidx) * H;
#pragma unroll
    for (int j = 0; j < 8; j++) {
      a0[j] = (_Float16)ar[q * 8 + j];
      a1[j] = (_Float16)ar[32 + q * 8 + j];
    }
  }
  f32x4 acc1 = {0.f, 0.f, 0.f, 0.f};
  acc1 = __builtin_amdgcn_mfma_f32_16x16x32_f16(a0, b1lo, acc1, 0, 0, 0);
  acc1 = __builtin_amdgcn_mfma_f32_16x16x32_f16(a1, b1hi, acc1, 0, 0, 0);
  f32x4 acc2 = {0.f, 0.f, 0.f, 0.f};
  if (out2) {
    acc2 = __builtin_amdgcn_mfma_f32_16x16x32_f16(a0, b2lo, acc2, 0, 0, 0);
    acc2 = __builtin_amdgcn_mfma_f32_16x16x32_f16(a1, b2hi, acc2, 0, 0, 0);
  }

  const float bj = bias ? bias[w * 16 + cidx] : 0.f;
  __syncthreads();   // Gs ready; all A loads drained before in-place stores
#pragma unroll
  for (int reg = 0; reg < 4; reg++) {
    const int r = q * 4 + reg;
    float v = acc1[reg] + bj;
    if (y) v += Gs[r * H + w * 16 + cidx];
    if (relu) v = fmaxf(v, 0.f);
    out1[(long)(rb + r) * H + w * 16 + cidx] = (_Float16)v;
    if (out2)
      out2[(long)(rb + r) * H + w * 16 + cidx] = (_Float16)acc2[reg];
  }
}

// Loc side: out = mean-gather(fp16 T rows) + x @ Wr + bias (opt relu).
__global__ __launch_bounds__(256, 4) void loc_gather_kernel(
    const int* __restrict__ nbr, const int* __restrict__ cnt,
    const _Float16* __restrict__ T, const float* __restrict__ x,
    float* __restrict__ out32, _Float16* __restrict__ out16,
    const float* __restrict__ Wr, const float* __restrict__ bias,
    int n, int relu)
{
  const int lane = threadIdx.x & 63;
  const int gw = (blockIdx.x * 256 + threadIdx.x) >> 6;
  const int nw = (gridDim.x * 256) >> 6;
  float wr[H];
#pragma unroll
  for (int k = 0; k < H; k++) wr[k] = Wr[k * H + lane];
  const float bj = bias[lane];
  for (int i = gw; i < n; i += nw) {
    const int c = cnt[i];
    const int cc = min(c, PAD_L);
    const int* nb = nbr + (long)i * PAD_L;
    float s0 = 0.f, s1 = 0.f, s2 = 0.f, s3 = 0.f;
    int e = 0;
    while (e < cc) {
      const int m = min(cc - e, 64);
      const int id = (lane < m) ? nb[e + lane] : 0;
      int k = 0;
      const int m4 = m & ~3;
      for (; k < m4; k += 4) {
        const int i0 = bcasti(id, k), i1 = bcasti(id, k + 1),
                  i2 = bcasti(id, k + 2), i3 = bcasti(id, k + 3);
        s0 += (float)T[(long)i0 * H + lane];
        s1 += (float)T[(long)i1 * H + lane];
        s2 += (float)T[(long)i2 * H + lane];
        s3 += (float)T[(long)i3 * H + lane];
      }
      for (; k < m; k++) s0 += (float)T[(long)bcasti(id, k) * H + lane];
      e += m;
    }
    const float agg = ((s0 + s1) + (s2 + s3)) / fmaxf((float)c, 1.0f);
    const float xv = x[i * H + lane];
    float a0 = 0.f, a1 = 0.f;
#pragma unroll
    for (int k = 0; k < H; k += 2) {
      a0 += bcastf(xv, k)     * wr[k];
      a1 += bcastf(xv, k + 1) * wr[k + 1];
    }
    float acc = agg + bj + a0 + a1;
    if (relu) acc = fmaxf(acc, 0.0f);
    if (out32) out32[i * H + lane] = acc;
    else       out16[i * H + lane] = (_Float16)acc;
  }
}

// out[e] = sum_j relu(P[r,j] + Q[c,j] + db1[j]) * dW2[j] + db2  (P,Q fp16)
__global__ __launch_bounds__(256, 4) void edge_kernel(
    const int* __restrict__ row, const int* __restrict__ col,
    const _Float16* __restrict__ P, const _Float16* __restrict__ Q,
    const float* __restrict__ db1, const float* __restrict__ dW2,
    const float* __restrict__ db2, float* __restrict__ out)
{
  const int lane = threadIdx.x & 63;
  const int gw = (blockIdx.x * 256 + threadIdx.x) >> 6;
  const int nw = (gridDim.x * 256) >> 6;
  const float bj = db1[lane];
  const float w2 = dW2[lane];
  const float b2 = db2[0];
  for (int e = gw * 4; e < NL; e += nw * 4) {
    const int n4 = min(NL - e, 4);
    float h[4];
#pragma unroll
    for (int k = 0; k < 4; k++) {
      if (k < n4) {
        const int r = row[e + k], c = col[e + k];
        const float p = (float)P[(long)r * H + lane];
        const float q = (float)Q[(long)c * H + lane];
        h[k] = fmaxf(p + q + bj, 0.0f) * w2;
      } else h[k] = 0.f;
    }
#pragma unroll
    for (int off = 1; off < 64; off <<= 1) {
#pragma unroll
      for (int k = 0; k < 4; k++) h[k] += __shfl_xor(h[k], off);
    }
    if (lane == 0) {
#pragma unroll
      for (int k = 0; k < 4; k++)
        if (k < n4) out[e + k] = h[k] + b2;
    }
  }
}

extern "C" void kernel_launch(void* const* d_in, const int* in_sizes, int n_in,
                              void* d_out, int out_size, void* d_ws, size_t ws_size,
                              hipStream_t stream) {
  const float* emb_loc = (const float*)d_in[0];
  const float* emb_exp = (const float*)d_in[1];
  const float* W1l_of  = (const float*)d_in[2];
  const float* b1_of   = (const float*)d_in[3];
  const float* W1r_of  = (const float*)d_in[4];
  const float* W1l_rev = (const float*)d_in[5];
  const float* b1_rev  = (const float*)d_in[6];
  const float* W1r_rev = (const float*)d_in[7];
  const float* W2l_of  = (const float*)d_in[8];
  const float* b2_of   = (const float*)d_in[9];
  const float* W2r_of  = (const float*)d_in[10];
  const float* W2l_rev = (const float*)d_in[11];
  const float* b2_rev  = (const float*)d_in[12];
  const float* W2r_rev = (const float*)d_in[13];
  const float* dW1     = (const float*)d_in[14];
  const float* db1     = (const float*)d_in[15];
  const float* dW2     = (const float*)d_in[16];
  const float* db2     = (const float*)d_in[17];
  const int*   edge_of = (const int*)d_in[18];
  const int*   eli     = (const int*)d_in[20];

  const int* src = edge_of;
  const int* dst = edge_of + NE;
  const int* row = eli;
  const int* col = eli + NL;

  if (ws_size < WS_NEED) return;

  char* ws = (char*)d_ws;
  int*            cnt_loc = (int*)(ws);
  int*            cnt_exp = (int*)(ws + 80000);
  int*            tickets = (int*)(ws + 880000);
  int*            nbr_loc = (int*)(ws + 880064);
  unsigned short* nbr_exp = (unsigned short*)(ws + 11120064);
  _Float16*       Ylh     = (_Float16*)(ws + 23920064);
  _Float16*       Y2fh    = (_Float16*)(ws + 26480064);
  float*          z_loc   = (float*)(ws + 29040064);
  _Float16*       PH      = (_Float16*)(ws + 34160064);
  _Float16*       ZE      = (_Float16*)(ws + 39280064);
  _Float16*       TH      = (_Float16*)(ws + 64880064);
  float*          Wf_q    = (float*)(ws + 90480064);
  float*          Wf_y2   = (float*)(ws + 90496448);
  float*          Wf_t2   = (float*)(ws + 90512832);
  float*          Wf_p    = (float*)(ws + 90529216);
  float*          bf_q    = (float*)(ws + 90545600);
  float*          bf_p    = (float*)(ws + 90545856);
  float*          out     = (float*)d_out;

  (void)hipMemsetAsync(ws, 0, 880064, stream);

  // fold + dense#1 + XCD-affine CSR fill, all ticket-dispensed
  mega_kernel<<<NFILL, 256, 0, stream>>>(src, dst, cnt_loc, cnt_exp,
      nbr_loc, nbr_exp, tickets, emb_loc, Ylh, W1l_of,
      W2r_of, W2l_of, W2l_rev, W2r_rev, dW1, b2_of, b2_rev,
      Wf_q, Wf_y2, Wf_t2, Wf_p, bf_q, bf_p);

  // ---- layer 1 ----
  // passA: z_exph = relu(emb_exp@W1r_of + gatherE(Ylh) + b1_of); T1h = emb_exp@W1l_rev
  mfma_pass_kernel<<<NEXP / 16, 256, 0, stream>>>(nbr_exp, cnt_exp, Ylh,
      emb_exp, (const _Float16*)nullptr, ZE, W1r_of, b1_of, 1, TH, W1l_rev);
  loc_gather_kernel<<<1250, 256, 0, stream>>>(nbr_loc, cnt_loc, TH,
      emb_loc, z_loc, (_Float16*)nullptr, W1r_rev, b1_rev, NLOC, 1);

  // ---- layer 2 + decoder transforms (folded: no relu on layer 2) ----
  dense_linear_kernel<<<1280, 256, 0, stream>>>(z_loc, Y2fh, Wf_y2, NLOC);
  // passB: Qh = z_exph@Wf_q + gatherE(Y2fh) + bf_q (in-place over ZE);
  //        T2'h = z_exph@Wf_t2 (over TH; T1h consumed)
  mfma_pass_kernel<<<NEXP / 16, 256, 0, stream>>>(nbr_exp, cnt_exp, Y2fh,
      (const float*)nullptr, ZE, ZE, Wf_q, bf_q, 0, TH, Wf_t2);
  // PH = gatherL(T2'h) + z_loc@Wf_p + bf_p   (decoder-left, folded, fp16 out)
  loc_gather_kernel<<<1250, 256, 0, stream>>>(nbr_loc, cnt_loc, TH,
      z_loc, (float*)nullptr, PH, Wf_p, bf_p, NLOC, 0);

  // ---- decoder edge pass ----
  edge_kernel<<<2048, 256, 0, stream>>>(row, col, PH, ZE,
                                        db1, dW2, db2, out);
}

// Round 3
// 527.140 us; speedup vs baseline: 1.6180x; 1.6180x over previous
//
#include <hip/hip_runtime.h>

#define H 64
#define NE 1500000
#define NLOC 20000
#define NEXP 200000
#define NL 400000
#define PAD_E 32
#define PAD_L 128

// ---- bucket-sort fill geometry ----
#define EB 896                        // experts per bucket (row LDS = 56KB)
#define NBE 224                       // ceil(200000/896)
#define LB 112                        // locs per bucket (row LDS = 56KB)
#define NBL 179                       // ceil(20000/112)
#define BIN_CHUNK 2048
#define NBIN ((NE + BIN_CHUNK - 1) / BIN_CHUNK)   // 733
#define EBSLOT 28                     // LDS slots per exp bucket per block
#define LBSLOT 32                     // LDS slots per loc bucket per block
#define ECAP 8192                     // exp queue capacity (lam 6696, +18 sigma)
#define LCAP 10240                    // loc queue capacity (lam 8380, +20 sigma)
#define FCAP 4096                     // fallback queue

// ---- workspace layout (bytes) ----
// cnt_loc [0,80000)  cnt_exp [80000,880000)
// nbr_loc [880064,11120064)  nbr_exp(u16) [11120064,23920064)
// Ylh(f16)  [23920064,26480064)   Y2fh(f16) [26480064,29040064)
// z_loc(f32)[29040064,34160064)   PH(f16)   [34160064,36720064)
// ZE(f16)   [39280064,64880064)   z_exph -> Qh (in-place)
// TH(f16)   [64880064,90480064)   T1h -> T2'h
//   (aliased pre-mfma: expQ [64880064,72220096) locQ [72220096,79551936)
//    qcnt [79551936,+1612) flbk_cnt [79553552) flbkQ [79554048,+32768))
// Wf_q [90480064) Wf_y2 [90496448) Wf_t2 [90512832) Wf_p [90529216)
// bf_q [90545600) bf_p [90545856)
#define WS_NEED 90546112ULL

typedef int vint4 __attribute__((ext_vector_type(4)));
typedef _Float16 f16x8 __attribute__((ext_vector_type(8)));
typedef float f32x4 __attribute__((ext_vector_type(4)));
typedef unsigned int u32;
typedef unsigned short u16;
typedef unsigned long long u64;

__device__ __forceinline__ float bcastf(float v, int k) {
  return __int_as_float(__builtin_amdgcn_readlane(__float_as_int(v), k));
}
__device__ __forceinline__ int bcasti(int v, int k) {
  return __builtin_amdgcn_readlane(v, k);
}

// ---------------- bucket-sort fill, pass 1: bin edges ----------------
// r1 evidence: WRITE_SIZE 132MB invariant to XCD affinity -> scattered
// sub-line stores are ~1 HBM transaction each (no write-allocate). Fix:
// group edges by destination in LDS, emit dense per-bucket runs.
__global__ __launch_bounds__(256) void bin_kernel(
    const int* __restrict__ src, const int* __restrict__ dst,
    u32* __restrict__ expQ, u32* __restrict__ locQ,
    int* __restrict__ qcnt, int* __restrict__ flbk_cnt,
    u64* __restrict__ flbkQ)
{
  __shared__ u32 eb[NBE * EBSLOT];   // 25088 B
  __shared__ u32 lb[NBL * LBSLOT];   // 22912 B
  __shared__ int ec[NBE], lc[NBL], ebase[NBE], lbase[NBL];  // 3224 B

  const int tid = threadIdx.x;
  for (int i = tid; i < NBE; i += 256) ec[i] = 0;
  for (int i = tid; i < NBL; i += 256) lc[i] = 0;
  __syncthreads();

  const long base = (long)blockIdx.x * BIN_CHUNK + tid * 8;
  if (base < NE) {   // NE % 8 == 0, so full 8-edge packet
    vint4 s0 = __builtin_nontemporal_load((const vint4*)(src + base));
    vint4 s1 = __builtin_nontemporal_load((const vint4*)(src + base + 4));
    vint4 d0 = __builtin_nontemporal_load((const vint4*)(dst + base));
    vint4 d1 = __builtin_nontemporal_load((const vint4*)(dst + base + 4));
    int ss[8] = {s0.x, s0.y, s0.z, s0.w, s1.x, s1.y, s1.z, s1.w};
    int dd[8] = {d0.x, d0.y, d0.z, d0.w, d1.x, d1.y, d1.z, d1.w};
#pragma unroll
    for (int k = 0; k < 8; k++) {
      const u32 d = (u32)dd[k], s = (u32)ss[k];
      {  // exp side: bucket by dst
        const u32 b = d / (u32)EB;
        const int pos = atomicAdd(&ec[b], 1);
        if (pos < EBSLOT) {
          eb[b * EBSLOT + pos] = ((d - b * EB) << 16) | s;
        } else {
          int fi = atomicAdd(flbk_cnt, 1);
          if (fi < FCAP) flbkQ[fi] = ((u64)d << 32) | (u64)s;   // side bit 0
        }
      }
      {  // loc side: bucket by src
        const u32 b = s / (u32)LB;
        const int pos = atomicAdd(&lc[b], 1);
        if (pos < LBSLOT) {
          lb[b * LBSLOT + pos] = ((s - b * LB) << 18) | d;
        } else {
          int fi = atomicAdd(flbk_cnt, 1);
          if (fi < FCAP) flbkQ[fi] = (1ULL << 63) | ((u64)s << 32) | (u64)d;
        }
      }
    }
  }
  __syncthreads();

  // reserve queue space (one global atomic per non-empty bucket, all parallel)
  for (int i = tid; i < NBE; i += 256) {
    const int c = min(ec[i], EBSLOT);
    ebase[i] = c ? atomicAdd(&qcnt[i], c) : 0;
  }
  for (int i = tid; i < NBL; i += 256) {
    const int c = min(lc[i], LBSLOT);
    lbase[i] = c ? atomicAdd(&qcnt[NBE + i], c) : 0;
  }
  __syncthreads();

  // flush dense runs (wave per bucket stripe)
  const int wid = tid >> 6, ln = tid & 63;
  for (int b = wid; b < NBE; b += 4) {
    const int c = min(ec[b], EBSLOT);
    if (ln < c) {
      const int idx = ebase[b] + ln;
      const u32 r = eb[b * EBSLOT + ln];
      if (idx < ECAP) {
        expQ[(long)b * ECAP + idx] = r;
      } else {
        int fi = atomicAdd(flbk_cnt, 1);
        if (fi < FCAP)
          flbkQ[fi] = ((u64)(b * EB + (r >> 16)) << 32) | (u64)(r & 0xFFFF);
      }
    }
  }
  for (int b = wid; b < NBL; b += 4) {
    const int c = min(lc[b], LBSLOT);
    if (ln < c) {
      const int idx = lbase[b] + ln;
      const u32 r = lb[b * LBSLOT + ln];
      if (idx < LCAP) {
        locQ[(long)b * LCAP + idx] = r;
      } else {
        int fi = atomicAdd(flbk_cnt, 1);
        if (fi < FCAP)
          flbkQ[fi] = (1ULL << 63) | ((u64)(b * LB + (r >> 18)) << 32) |
                      (u64)(r & 0x3FFFF);
      }
    }
  }
}

// ---------------- bucket-sort fill, pass 2: build padded CSR ----------------
// Per bucket: scatter records in LDS, then write nbr rows as FULL lines.
__global__ __launch_bounds__(256) void build_kernel(
    const u32* __restrict__ expQ, const u32* __restrict__ locQ,
    const int* __restrict__ qcnt,
    u16* __restrict__ nbr_exp, int* __restrict__ nbr_loc,
    int* __restrict__ cnt_exp, int* __restrict__ cnt_loc)
{
  __shared__ char ldsraw[60928];
  const int tid = threadIdx.x;
  if (blockIdx.x < NBE) {
    const int b = blockIdx.x;
    u16* rows = (u16*)ldsraw;                 // EB*PAD_E u16 = 57344 B
    int* cnts = (int*)(ldsraw + 57344);       // EB ints  = 3584 B
    for (int i = tid; i < EB; i += 256) cnts[i] = 0;
    __syncthreads();
    const int n = min(qcnt[b], ECAP);
    for (int i = tid; i < n; i += 256) {
      const u32 r = expQ[(long)b * ECAP + i];
      const int nl = (int)(r >> 16);
      const int pos = atomicAdd(&cnts[nl], 1);
      if (pos < PAD_E) rows[nl * PAD_E + pos] = (u16)(r & 0xFFFF);
    }
    __syncthreads();
    const int node0 = b * EB;
    const int nn = min(EB, NEXP - node0);
    u32* grows = (u32*)(nbr_exp + (long)node0 * PAD_E);
    const u32* lrows = (const u32*)rows;
    for (int j = tid; j < nn * (PAD_E / 2); j += 256) grows[j] = lrows[j];
    for (int i = tid; i < nn; i += 256) cnt_exp[node0 + i] = cnts[i];
  } else {
    const int b = blockIdx.x - NBE;
    int* rows = (int*)ldsraw;                 // LB*PAD_L int = 57344 B
    int* cnts = (int*)(ldsraw + 57344);       // LB ints = 448 B
    for (int i = tid; i < LB; i += 256) cnts[i] = 0;
    __syncthreads();
    const int n = min(qcnt[NBE + b], LCAP);
    for (int i = tid; i < n; i += 256) {
      const u32 r = locQ[(long)b * LCAP + i];
      const int sl = (int)(r >> 18);
      const int pos = atomicAdd(&cnts[sl], 1);
      if (pos < PAD_L) rows[sl * PAD_L + pos] = (int)(r & 0x3FFFF);
    }
    __syncthreads();
    const int node0 = b * LB;
    const int nn = min(LB, NLOC - node0);
    int* grows = nbr_loc + (long)node0 * PAD_L;
    for (int j = tid; j < nn * PAD_L; j += 256) grows[j] = rows[j];
    for (int i = tid; i < nn; i += 256) cnt_loc[node0 + i] = cnts[i];
  }
}

// Fold layer-2 weights through the decoder (+ block 5: drain fill fallback).
__global__ __launch_bounds__(256) void fold_kernel(
    const float* __restrict__ W2r_of, const float* __restrict__ W2l_of,
    const float* __restrict__ W2l_rev, const float* __restrict__ W2r_rev,
    const float* __restrict__ dW1, const float* __restrict__ b2_of,
    const float* __restrict__ b2_rev,
    float* __restrict__ Wf_q, float* __restrict__ Wf_y2,
    float* __restrict__ Wf_t2, float* __restrict__ Wf_p,
    float* __restrict__ bf_q, float* __restrict__ bf_p,
    const int* __restrict__ flbk_cnt, const u64* __restrict__ flbkQ,
    u16* __restrict__ nbr_exp, int* __restrict__ nbr_loc,
    int* __restrict__ cnt_exp, int* __restrict__ cnt_loc)
{
  const int lane = threadIdx.x & 63;
  const int w = threadIdx.x >> 6;
  const float* dW1a = dW1;
  const float* dW1b = dW1 + H * H;
  if (blockIdx.x < 4) {
    const float* A; const float* B; float* C;
    switch (blockIdx.x) {
      case 0:  A = W2r_of;  B = dW1b; C = Wf_q;  break;
      case 1:  A = W2l_of;  B = dW1b; C = Wf_y2; break;
      case 2:  A = W2l_rev; B = dW1a; C = Wf_t2; break;
      default: A = W2r_rev; B = dW1a; C = Wf_p;  break;
    }
    float b[H];
#pragma unroll
    for (int k = 0; k < H; k++) b[k] = B[k * H + lane];
    for (int r = w * 16; r < w * 16 + 16; r++) {
      const float xv = A[r * H + lane];
      float a0 = 0.f, a1 = 0.f;
#pragma unroll
      for (int k = 0; k < H; k += 2) {
        a0 += bcastf(xv, k)     * b[k];
        a1 += bcastf(xv, k + 1) * b[k + 1];
      }
      C[r * H + lane] = a0 + a1;
    }
  } else if (blockIdx.x == 4) {
    if (w < 2) {
      const float* bv_src = (w == 0) ? b2_of : b2_rev;
      const float* B      = (w == 0) ? dW1b  : dW1a;
      float* o            = (w == 0) ? bf_q  : bf_p;
      float wk[H];
#pragma unroll
      for (int k = 0; k < H; k++) wk[k] = B[k * H + lane];
      const float bv = bv_src[lane];
      float a = 0.f;
#pragma unroll
      for (int k = 0; k < H; k++) a += bcastf(bv, k) * wk[k];
      o[lane] = a;
    }
  } else {
    // drain fallback queue (rare Poisson-tail edges; keeps fill exact)
    const int n = min(*flbk_cnt, FCAP);
    for (int i = threadIdx.x; i < n; i += 256) {
      const u64 rec = flbkQ[i];
      const int node = (int)((rec >> 32) & 0x3FFFF);
      const int val  = (int)(rec & 0x3FFFF);
      if ((rec >> 63) == 0) {
        int pos = atomicAdd(&cnt_exp[node], 1);
        if (pos < PAD_E) nbr_exp[(long)node * PAD_E + pos] = (u16)val;
      } else {
        int pos = atomicAdd(&cnt_loc[node], 1);
        if (pos < PAD_L) nbr_loc[(long)node * PAD_L + pos] = val;
      }
    }
  }
}

// out16 = x @ W (no bias); fp32 in, fp16 out. 20K rows.
__global__ __launch_bounds__(256, 4) void dense_linear_kernel(
    const float* __restrict__ x, _Float16* __restrict__ out16,
    const float* __restrict__ W, int n)
{
  const int lane = threadIdx.x & 63;
  const int gw = (blockIdx.x * 256 + threadIdx.x) >> 6;
  const int nw = (gridDim.x * 256) >> 6;
  float w[H];
#pragma unroll
  for (int k = 0; k < H; k++) w[k] = W[k * H + lane];
  for (int i = gw; i < n; i += nw) {
    const float xv = x[i * H + lane];
    float a0 = 0.f, a1 = 0.f;
#pragma unroll
    for (int k = 0; k < H; k += 2) {
      a0 += bcastf(xv, k)     * w[k];
      a1 += bcastf(xv, k + 1) * w[k + 1];
    }
    out16[i * H + lane] = (_Float16)(a0 + a1);
  }
}

// Exp-side MFMA pass (dual-B, optional gather/bias/relu). Block = 16 rows.
__global__ __launch_bounds__(256, 4) void mfma_pass_kernel(
    const unsigned short* __restrict__ nbr, const int* __restrict__ cnt,
    const _Float16* __restrict__ y,
    const float* a32, const _Float16* a16,
    _Float16* out1, const float* __restrict__ W1,
    const float* __restrict__ bias, int relu,
    _Float16* out2, const float* __restrict__ W2)
{
  const int w = threadIdx.x >> 6;
  const int lane = threadIdx.x & 63;
  const int q = lane >> 4;
  const int cidx = lane & 15;
  const int rb = blockIdx.x * 16;

  __shared__ float Gs[16 * H];

  f16x8 b1lo, b1hi, b2lo, b2hi;
#pragma unroll
  for (int j = 0; j < 8; j++) {
    b1lo[j] = (_Float16)W1[(q * 8 + j) * H + w * 16 + cidx];
    b1hi[j] = (_Float16)W1[(32 + q * 8 + j) * H + w * 16 + cidx];
  }
  if (out2) {
#pragma unroll
    for (int j = 0; j < 8; j++) {
      b2lo[j] = (_Float16)W2[(q * 8 + j) * H + w * 16 + cidx];
      b2hi[j] = (_Float16)W2[(32 + q * 8 + j) * H + w * 16 + cidx];
    }
  }

  if (y) {
    for (int rr = 0; rr < 4; rr++) {
      const int i = rb + w * 4 + rr;
      const int c = cnt[i];
      const int cc = min(c, PAD_E);
      const unsigned short* nb = nbr + (long)i * PAD_E;
      float s0 = 0.f, s1 = 0.f, s2 = 0.f, s3 = 0.f;
      const int id = (lane < cc) ? (int)nb[lane] : 0;
      int k = 0;
      const int m4 = cc & ~3;
      for (; k < m4; k += 4) {
        const int i0 = bcasti(id, k), i1 = bcasti(id, k + 1),
                  i2 = bcasti(id, k + 2), i3 = bcasti(id, k + 3);
        s0 += (float)y[(long)i0 * H + lane];
        s1 += (float)y[(long)i1 * H + lane];
        s2 += (float)y[(long)i2 * H + lane];
        s3 += (float)y[(long)i3 * H + lane];
      }
      for (; k < cc; k++) s0 += (float)y[(long)bcasti(id, k) * H + lane];
      Gs[(w * 4 + rr) * H + lane] =
          ((s0 + s1) + (s2 + s3)) / fmaxf((float)c, 1.0f);
    }
  }

  f16x8 a0, a1;
  if (a16) {
    const _Float16* ar = a16 + (long)(rb + cidx) * H;
    a0 = *(const f16x8*)(ar + q * 8);
    a1 = *(const f16x8*)(ar + 32 + q * 8);
  } else {
    const float* ar = a32 + (long)(rb + cidx) * H;
#pragma unroll
    for (int j = 0; j < 8; j++) {
      a0[j] = (_Float16)ar[q * 8 + j];
      a1[j] = (_Float16)ar[32 + q * 8 + j];
    }
  }
  f32x4 acc1 = {0.f, 0.f, 0.f, 0.f};
  acc1 = __builtin_amdgcn_mfma_f32_16x16x32_f16(a0, b1lo, acc1, 0, 0, 0);
  acc1 = __builtin_amdgcn_mfma_f32_16x16x32_f16(a1, b1hi, acc1, 0, 0, 0);
  f32x4 acc2 = {0.f, 0.f, 0.f, 0.f};
  if (out2) {
    acc2 = __builtin_amdgcn_mfma_f32_16x16x32_f16(a0, b2lo, acc2, 0, 0, 0);
    acc2 = __builtin_amdgcn_mfma_f32_16x16x32_f16(a1, b2hi, acc2, 0, 0, 0);
  }

  const float bj = bias ? bias[w * 16 + cidx] : 0.f;
  __syncthreads();   // Gs ready; all A loads drained before in-place stores
#pragma unroll
  for (int reg = 0; reg < 4; reg++) {
    const int r = q * 4 + reg;
    float v = acc1[reg] + bj;
    if (y) v += Gs[r * H + w * 16 + cidx];
    if (relu) v = fmaxf(v, 0.f);
    out1[(long)(rb + r) * H + w * 16 + cidx] = (_Float16)v;
    if (out2)
      out2[(long)(rb + r) * H + w * 16 + cidx] = (_Float16)acc2[reg];
  }
}

// Loc side: out = mean-gather(fp16 T rows) + x @ Wr + bias (opt relu).
__global__ __launch_bounds__(256, 4) void loc_gather_kernel(
    const int* __restrict__ nbr, const int* __restrict__ cnt,
    const _Float16* __restrict__ T, const float* __restrict__ x,
    float* __restrict__ out32, _Float16* __restrict__ out16,
    const float* __restrict__ Wr, const float* __restrict__ bias,
    int n, int relu)
{
  const int lane = threadIdx.x & 63;
  const int gw = (blockIdx.x * 256 + threadIdx.x) >> 6;
  const int nw = (gridDim.x * 256) >> 6;
  float wr[H];
#pragma unroll
  for (int k = 0; k < H; k++) wr[k] = Wr[k * H + lane];
  const float bj = bias[lane];
  for (int i = gw; i < n; i += nw) {
    const int c = cnt[i];
    const int cc = min(c, PAD_L);
    const int* nb = nbr + (long)i * PAD_L;
    float s0 = 0.f, s1 = 0.f, s2 = 0.f, s3 = 0.f;
    int e = 0;
    while (e < cc) {
      const int m = min(cc - e, 64);
      const int id = (lane < m) ? nb[e + lane] : 0;
      int k = 0;
      const int m4 = m & ~3;
      for (; k < m4; k += 4) {
        const int i0 = bcasti(id, k), i1 = bcasti(id, k + 1),
                  i2 = bcasti(id, k + 2), i3 = bcasti(id, k + 3);
        s0 += (float)T[(long)i0 * H + lane];
        s1 += (float)T[(long)i1 * H + lane];
        s2 += (float)T[(long)i2 * H + lane];
        s3 += (float)T[(long)i3 * H + lane];
      }
      for (; k < m; k++) s0 += (float)T[(long)bcasti(id, k) * H + lane];
      e += m;
    }
    const float agg = ((s0 + s1) + (s2 + s3)) / fmaxf((float)c, 1.0f);
    const float xv = x[i * H + lane];
    float a0 = 0.f, a1 = 0.f;
#pragma unroll
    for (int k = 0; k < H; k += 2) {
      a0 += bcastf(xv, k)     * wr[k];
      a1 += bcastf(xv, k + 1) * wr[k + 1];
    }
    float acc = agg + bj + a0 + a1;
    if (relu) acc = fmaxf(acc, 0.0f);
    if (out32) out32[i * H + lane] = acc;
    else       out16[i * H + lane] = (_Float16)acc;
  }
}

// out[e] = sum_j relu(P[r,j] + Q[c,j] + db1[j]) * dW2[j] + db2  (P,Q fp16)
__global__ __launch_bounds__(256, 4) void edge_kernel(
    const int* __restrict__ row, const int* __restrict__ col,
    const _Float16* __restrict__ P, const _Float16* __restrict__ Q,
    const float* __restrict__ db1, const float* __restrict__ dW2,
    const float* __restrict__ db2, float* __restrict__ out)
{
  const int lane = threadIdx.x & 63;
  const int gw = (blockIdx.x * 256 + threadIdx.x) >> 6;
  const int nw = (gridDim.x * 256) >> 6;
  const float bj = db1[lane];
  const float w2 = dW2[lane];
  const float b2 = db2[0];
  for (int e = gw * 4; e < NL; e += nw * 4) {
    const int n4 = min(NL - e, 4);
    float h[4];
#pragma unroll
    for (int k = 0; k < 4; k++) {
      if (k < n4) {
        const int r = row[e + k], c = col[e + k];
        const float p = (float)P[(long)r * H + lane];
        const float q = (float)Q[(long)c * H + lane];
        h[k] = fmaxf(p + q + bj, 0.0f) * w2;
      } else h[k] = 0.f;
    }
#pragma unroll
    for (int off = 1; off < 64; off <<= 1) {
#pragma unroll
      for (int k = 0; k < 4; k++) h[k] += __shfl_xor(h[k], off);
    }
    if (lane == 0) {
#pragma unroll
      for (int k = 0; k < 4; k++)
        if (k < n4) out[e + k] = h[k] + b2;
    }
  }
}

extern "C" void kernel_launch(void* const* d_in, const int* in_sizes, int n_in,
                              void* d_out, int out_size, void* d_ws, size_t ws_size,
                              hipStream_t stream) {
  const float* emb_loc = (const float*)d_in[0];
  const float* emb_exp = (const float*)d_in[1];
  const float* W1l_of  = (const float*)d_in[2];
  const float* b1_of   = (const float*)d_in[3];
  const float* W1r_of  = (const float*)d_in[4];
  const float* W1l_rev = (const float*)d_in[5];
  const float* b1_rev  = (const float*)d_in[6];
  const float* W1r_rev = (const float*)d_in[7];
  const float* W2l_of  = (const float*)d_in[8];
  const float* b2_of   = (const float*)d_in[9];
  const float* W2r_of  = (const float*)d_in[10];
  const float* W2l_rev = (const float*)d_in[11];
  const float* b2_rev  = (const float*)d_in[12];
  const float* W2r_rev = (const float*)d_in[13];
  const float* dW1     = (const float*)d_in[14];
  const float* db1     = (const float*)d_in[15];
  const float* dW2     = (const float*)d_in[16];
  const float* db2     = (const float*)d_in[17];
  const int*   edge_of = (const int*)d_in[18];
  const int*   eli     = (const int*)d_in[20];

  const int* src = edge_of;
  const int* dst = edge_of + NE;
  const int* row = eli;
  const int* col = eli + NL;

  if (ws_size < WS_NEED) return;

  char* ws = (char*)d_ws;
  int*            cnt_loc = (int*)(ws);
  int*            cnt_exp = (int*)(ws + 80000);
  int*            nbr_loc = (int*)(ws + 880064);
  unsigned short* nbr_exp = (unsigned short*)(ws + 11120064);
  _Float16*       Ylh     = (_Float16*)(ws + 23920064);
  _Float16*       Y2fh    = (_Float16*)(ws + 26480064);
  float*          z_loc   = (float*)(ws + 29040064);
  _Float16*       PH      = (_Float16*)(ws + 34160064);
  _Float16*       ZE      = (_Float16*)(ws + 39280064);
  _Float16*       TH      = (_Float16*)(ws + 64880064);
  // fill-time aliases over the TH region (dead until mfma pass #1)
  u32*            expQ    = (u32*)(ws + 64880064);
  u32*            locQ    = (u32*)(ws + 72220096);
  int*            qcnt    = (int*)(ws + 79551936);
  int*            flbk    = (int*)(ws + 79553552);
  u64*            flbkQ   = (u64*)(ws + 79554048);
  float*          Wf_q    = (float*)(ws + 90480064);
  float*          Wf_y2   = (float*)(ws + 90496448);
  float*          Wf_t2   = (float*)(ws + 90512832);
  float*          Wf_p    = (float*)(ws + 90529216);
  float*          bf_q    = (float*)(ws + 90545600);
  float*          bf_p    = (float*)(ws + 90545856);
  float*          out     = (float*)d_out;

  // zero queue counters + fallback counter only (cnt arrays fully written
  // by build_kernel; no 880KB memset needed anymore)
  (void)hipMemsetAsync(ws + 79551936, 0, 2048, stream);

  // ---- CSR fill: bin -> build (full-line writes) ----
  bin_kernel<<<NBIN, 256, 0, stream>>>(src, dst, expQ, locQ, qcnt, flbk, flbkQ);
  build_kernel<<<NBE + NBL, 256, 0, stream>>>(expQ, locQ, qcnt,
      nbr_exp, nbr_loc, cnt_exp, cnt_loc);
  fold_kernel<<<6, 256, 0, stream>>>(W2r_of, W2l_of, W2l_rev, W2r_rev,
                                     dW1, b2_of, b2_rev,
                                     Wf_q, Wf_y2, Wf_t2, Wf_p, bf_q, bf_p,
                                     flbk, flbkQ, nbr_exp, nbr_loc,
                                     cnt_exp, cnt_loc);

  // ---- layer 1 ----
  dense_linear_kernel<<<1280, 256, 0, stream>>>(emb_loc, Ylh, W1l_of, NLOC);
  // passA: z_exph = relu(emb_exp@W1r_of + gatherE(Ylh) + b1_of); T1h = emb_exp@W1l_rev
  mfma_pass_kernel<<<NEXP / 16, 256, 0, stream>>>(nbr_exp, cnt_exp, Ylh,
      emb_exp, (const _Float16*)nullptr, ZE, W1r_of, b1_of, 1, TH, W1l_rev);
  loc_gather_kernel<<<1250, 256, 0, stream>>>(nbr_loc, cnt_loc, TH,
      emb_loc, z_loc, (_Float16*)nullptr, W1r_rev, b1_rev, NLOC, 1);

  // ---- layer 2 + decoder transforms (folded: no relu on layer 2) ----
  dense_linear_kernel<<<1280, 256, 0, stream>>>(z_loc, Y2fh, Wf_y2, NLOC);
  // passB: Qh = z_exph@Wf_q + gatherE(Y2fh) + bf_q (in-place over ZE);
  //        T2'h = z_exph@Wf_t2 (over TH; T1h consumed)
  mfma_pass_kernel<<<NEXP / 16, 256, 0, stream>>>(nbr_exp, cnt_exp, Y2fh,
      (const float*)nullptr, ZE, ZE, Wf_q, bf_q, 0, TH, Wf_t2);
  // PH = gatherL(T2'h) + z_loc@Wf_p + bf_p   (decoder-left, folded, fp16 out)
  loc_gather_kernel<<<1250, 256, 0, stream>>>(nbr_loc, cnt_loc, TH,
      z_loc, (float*)nullptr, PH, Wf_p, bf_p, NLOC, 0);

  // ---- decoder edge pass ----
  edge_kernel<<<2048, 256, 0, stream>>>(row, col, PH, ZE,
                                        db1, dW2, db2, out);
}